// Round 3
// baseline (1136.428 us; speedup 1.0000x reference)
//
#include <hip/hip_runtime.h>
#include <hip/hip_fp16.h>

#define D      256
#define NNODES 50000
#define KNBR   32

// ---------------------------------------------------------------------------
// Kernel 1: h[n][o] = sum_i x[n][i]*W[o][i], fp32 compute, fp16 store.
// BM=BN=128, BK=32, 256 thr, 8x8 microtile. global_load_lds staging,
// double-buffered LDS, XOR-swizzled float4 layout (conflict-free reads).
// ---------------------------------------------------------------------------
#define BM 128
#define BN 128
#define BK 32
#define NT (D / BK)          // 8 k-tiles
#define TILE_F4 (BM * BK / 4)  // 1024 float4 per tile array

__device__ __forceinline__ void gll16(const void* g, void* l) {
  __builtin_amdgcn_global_load_lds(
      (const __attribute__((address_space(1))) void*)g,
      (__attribute__((address_space(3))) void*)l, 16, 0, 0);
}

__global__ __launch_bounds__(256, 2)
void gemm_xwT(const float* __restrict__ x, const float* __restrict__ W,
              __half* __restrict__ h) {
  __shared__ __align__(16) float xs[2][BM * BK];
  __shared__ __align__(16) float ws[2][BN * BK];

  const int tid  = threadIdx.x;
  const int lane = tid & 63;
  const int wv   = tid >> 6;        // wave 0..3
  const int tx   = tid & 15;        // col group 0..15
  const int ty   = tid >> 4;        // row group 0..15
  const int brow = blockIdx.x * BM;
  const int bcol = blockIdx.y * BN;

  float acc[8][8];
#pragma unroll
  for (int i = 0; i < 8; i++)
#pragma unroll
    for (int j = 0; j < 8; j++) acc[i][j] = 0.f;

  // Stage k-tile t into buffer buf. Linear LDS dest (global_load_lds rule);
  // bank-swizzle achieved by pre-swizzling the GLOBAL source column chunk:
  // float4 (r, c4) holds data of column chunk c4 ^ (r&7).
  auto stage = [&](int buf, int t) {
    const int k0 = t * BK;
#pragma unroll
    for (int q = 0; q < 4; q++) {
      int f   = (wv * 4 + q) * 64 + lane;    // flat float4 idx 0..1023
      int r   = f >> 3;                      // 8 float4 per row
      int c4s = (f & 7) ^ (r & 7);           // pre-swizzled source chunk
      int gx  = brow + r;
      int sx  = gx < NNODES ? gx : NNODES - 1;
      gll16(&x[(size_t)sx * D + k0 + c4s * 4], &xs[buf][f * 4]);
      gll16(&W[(size_t)(bcol + r) * D + k0 + c4s * 4], &ws[buf][f * 4]);
    }
  };

  stage(0, 0);
  asm volatile("s_waitcnt vmcnt(0)" ::: "memory");
  __builtin_amdgcn_s_barrier();
  __builtin_amdgcn_sched_barrier(0);

  for (int t = 0; t < NT; ++t) {
    const int cur = t & 1;
    if (t + 1 < NT) stage(cur ^ 1, t + 1);

#pragma unroll
    for (int kk4 = 0; kk4 < BK / 4; kk4++) {   // 8 chunks of 4 k
      float4 a[8], b[8];
#pragma unroll
      for (int i = 0; i < 8; i++) {
        int m = ty + 16 * i;
        a[i] = *reinterpret_cast<const float4*>(
            &xs[cur][(m * 8 + (kk4 ^ (m & 7))) * 4]);
      }
#pragma unroll
      for (int j = 0; j < 8; j++) {
        int n = tx + 16 * j;
        b[j] = *reinterpret_cast<const float4*>(
            &ws[cur][(n * 8 + (kk4 ^ (n & 7))) * 4]);
      }
#pragma unroll
      for (int i = 0; i < 8; i++)
#pragma unroll
        for (int j = 0; j < 8; j++) {
          acc[i][j] += a[i].x * b[j].x;
          acc[i][j] += a[i].y * b[j].y;
          acc[i][j] += a[i].z * b[j].z;
          acc[i][j] += a[i].w * b[j].w;
        }
    }

    if (t + 1 < NT) {
      asm volatile("s_waitcnt vmcnt(0)" ::: "memory");  // next tile landed
      __builtin_amdgcn_s_barrier();                     // no full drain
      __builtin_amdgcn_sched_barrier(0);
    }
  }

#pragma unroll
  for (int i = 0; i < 8; i++) {
    int grow = brow + ty + 16 * i;
    if (grow < NNODES) {
#pragma unroll
      for (int j = 0; j < 8; j++)
        h[(size_t)grow * D + bcol + tx + 16 * j] = __float2half(acc[i][j]);
    }
  }
}

// ---------------------------------------------------------------------------
// Kernel 2: per node, 128 threads x half2; two interleaved 32-sorts;
// mean of ranks 14..17.
// ---------------------------------------------------------------------------
template <int P, int K>
__device__ __forceinline__ void oem_pass(float* v) {
#pragma unroll
  for (int j = K % P; j + K < 32; j += 2 * K) {
#pragma unroll
    for (int i = 0; i < K; i++) {
      if (i + j + K < 32 && ((i + j) / (2 * P) == (i + j + K) / (2 * P))) {
        float lo = fminf(v[i + j], v[i + j + K]);
        float hi = fmaxf(v[i + j], v[i + j + K]);
        v[i + j] = lo;
        v[i + j + K] = hi;
      }
    }
  }
}

__device__ __forceinline__ void sort32(float* v) {
  oem_pass<1, 1>(v);
  oem_pass<2, 2>(v);  oem_pass<2, 1>(v);
  oem_pass<4, 4>(v);  oem_pass<4, 2>(v);  oem_pass<4, 1>(v);
  oem_pass<8, 8>(v);  oem_pass<8, 4>(v);  oem_pass<8, 2>(v);  oem_pass<8, 1>(v);
  oem_pass<16, 16>(v); oem_pass<16, 8>(v); oem_pass<16, 4>(v);
  oem_pass<16, 2>(v);  oem_pass<16, 1>(v);
}

__global__ __launch_bounds__(128, 4)
void trimmed_gather(const __half* __restrict__ h, const int* __restrict__ nbrs,
                    float* __restrict__ out) {
  const int o2 = threadIdx.x;           // channel pair 0..127

  for (int n = blockIdx.x; n < NNODES; n += gridDim.x) {
    float vx[KNBR], vy[KNBR];
#pragma unroll
    for (int k = 0; k < KNBR; k++) {
      int r = nbrs[n * KNBR + k];       // block-uniform -> scalar load
      __half2 t = *reinterpret_cast<const __half2*>(&h[(size_t)r * D + o2 * 2]);
      float2 f = __half22float2(t);
      vx[k] = f.x;
      vy[k] = f.y;
    }

    sort32(vx);
    sort32(vy);

    float2 res;
    res.x = (vx[14] + vx[15] + vx[16] + vx[17]) * 0.25f;
    res.y = (vy[14] + vy[15] + vy[16] + vy[17]) * 0.25f;
    *reinterpret_cast<float2*>(&out[n * D + o2 * 2]) = res;
  }
}

// ---------------------------------------------------------------------------
extern "C" void kernel_launch(void* const* d_in, const int* in_sizes, int n_in,
                              void* d_out, int out_size, void* d_ws, size_t ws_size,
                              hipStream_t stream) {
  const float* x    = (const float*)d_in[0];
  const int*   nbrs = (const int*)d_in[1];
  const float* W    = (const float*)d_in[2];
  float*       out  = (float*)d_out;
  __half*      h    = (__half*)d_ws;   // 50000*256*2 = 25.6 MB scratch

  dim3 g1((NNODES + BM - 1) / BM, D / BN);
  gemm_xwT<<<g1, dim3(256), 0, stream>>>(x, W, h);
  trimmed_gather<<<dim3(8192), dim3(128), 0, stream>>>(h, nbrs, out);
}

// Round 5
// 292.253 us; speedup vs baseline: 3.8885x; 3.8885x over previous
//
#include <hip/hip_runtime.h>
#include <hip/hip_fp16.h>

#define D      256
#define NNODES 50000
#define KNBR   32
#define NGRP   8      // channel groups
#define GRPC   32     // channels per group

typedef _Float16 h8 __attribute__((ext_vector_type(8)));
typedef _Float16 h2 __attribute__((ext_vector_type(2)));
typedef float    f4 __attribute__((ext_vector_type(4)));

// Packed half min/max (gfx950 VOP3P). ROCm headers' __hmin2 takes __half, so
// use the instruction directly.
__device__ __forceinline__ h2 h2min(h2 a, h2 b) {
  h2 d;
  asm("v_pk_min_f16 %0, %1, %2" : "=v"(d) : "v"(a), "v"(b));
  return d;
}
__device__ __forceinline__ h2 h2max(h2 a, h2 b) {
  h2 d;
  asm("v_pk_max_f16 %0, %1, %2" : "=v"(d) : "v"(a), "v"(b));
  return d;
}

// ws layout:
//   h_blk : _Float16 [NGRP][NNODES][GRPC]          25,600,000 B
//   Whi   : _Float16 [256*256]                     at +25,600,000
//   Wlo   : _Float16 [256*256]                     at +25,731,072

// ---------------------------------------------------------------------------
// Kernel 0: split W into fp16 hi/lo pair (Whi + Wlo ~= W to ~2^-22 rel).
// ---------------------------------------------------------------------------
__global__ void wcvt(const float* __restrict__ W, _Float16* __restrict__ whi,
                     _Float16* __restrict__ wlo) {
  int i = (blockIdx.x * 256 + threadIdx.x) * 4;   // 64 blocks cover 65536
  float4 w = *(const float4*)&W[i];
  float wf[4] = {w.x, w.y, w.z, w.w};
  union { _Float16 h[4]; uint2 u; } H, L;
#pragma unroll
  for (int e = 0; e < 4; e++) {
    _Float16 hi = (_Float16)wf[e];
    H.h[e] = hi;
    L.h[e] = (_Float16)(wf[e] - (float)hi);
  }
  *(uint2*)&whi[i] = H.u;
  *(uint2*)&wlo[i] = L.u;
}

// ---------------------------------------------------------------------------
// Kernel 1: h = x*W^T via 16x16x32 f16 MFMA, split-precision, LDS-free.
// Block = 64 rows x 256 cols, 4 waves; wave = 16 rows x 16 col-tiles.
// Output layout: h_blk[g][n][oc], g = o>>5, oc = o&31 (fp16).
// ---------------------------------------------------------------------------
__global__ __launch_bounds__(256, 4)
void gemm_mfma(const float* __restrict__ x, const _Float16* __restrict__ Whi,
               const _Float16* __restrict__ Wlo, _Float16* __restrict__ hblk) {
  const int tid  = threadIdx.x;
  const int lane = tid & 63;
  const int wv   = tid >> 6;
  const int c    = lane & 15;   // fragment row (A) / col (B)
  const int ko   = lane >> 4;   // k-chunk 0..3
  const int brow = blockIdx.x * 64;

  int arow = brow + wv * 16 + c;
  if (arow >= NNODES) arow = NNODES - 1;   // clamp loads; stores guarded

  f4 acc[16];
#pragma unroll
  for (int j = 0; j < 16; j++) acc[j] = (f4)(0.f);

  for (int ks = 0; ks < 8; ks++) {
    const int k0 = ks * 32 + ko * 8;
    const float* ap = &x[(size_t)arow * D + k0];
    float4 x0 = *(const float4*)ap;
    float4 x1 = *(const float4*)(ap + 4);
    float xf[8] = {x0.x, x0.y, x0.z, x0.w, x1.x, x1.y, x1.z, x1.w};
    h8 ahi, alo;
#pragma unroll
    for (int e = 0; e < 8; e++) {
      _Float16 hi = (_Float16)xf[e];
      ahi[e] = hi;
      alo[e] = (_Float16)(xf[e] - (float)hi);
    }
#pragma unroll
    for (int j = 0; j < 16; j++) {
      const size_t wb = (size_t)(j * 16 + c) * D + k0;
      h8 bhi = *(const h8*)&Whi[wb];
      h8 blo = *(const h8*)&Wlo[wb];
      acc[j] = __builtin_amdgcn_mfma_f32_16x16x32_f16(ahi, bhi, acc[j], 0, 0, 0);
      acc[j] = __builtin_amdgcn_mfma_f32_16x16x32_f16(ahi, blo, acc[j], 0, 0, 0);
      acc[j] = __builtin_amdgcn_mfma_f32_16x16x32_f16(alo, bhi, acc[j], 0, 0, 0);
    }
  }

  // C/D layout (HW-verified): col = lane&15 (=c), row = (lane>>4)*4 + reg.
#pragma unroll
  for (int j = 0; j < 16; j++) {
    const int g  = j >> 1;
    const int oc = (j & 1) * 16 + c;
#pragma unroll
    for (int r = 0; r < 4; r++) {
      const int n = brow + wv * 16 + ko * 4 + r;
      if (n < NNODES)
        hblk[((size_t)g * NNODES + n) * GRPC + oc] = (_Float16)acc[j][r];
    }
  }
}

// ---------------------------------------------------------------------------
// Kernel 2: trimmed-mean gather, channel-group blocked (per-XCD L2 resident).
// Block = (group g, 16 nodes) x 256 threads; thread = (node, h2 pair).
// Packed fp16 sort: v_pk_min/max_f16 = 2 channels per compare-exchange.
// ---------------------------------------------------------------------------
template <int P, int K>
__device__ __forceinline__ void oem_pass(h2* v) {
#pragma unroll
  for (int j = K % P; j + K < 32; j += 2 * K) {
#pragma unroll
    for (int i = 0; i < K; i++) {
      if (i + j + K < 32 && ((i + j) / (2 * P) == (i + j + K) / (2 * P))) {
        h2 lo = h2min(v[i + j], v[i + j + K]);
        h2 hi = h2max(v[i + j], v[i + j + K]);
        v[i + j] = lo;
        v[i + j + K] = hi;
      }
    }
  }
}

__device__ __forceinline__ void sort32(h2* v) {
  oem_pass<1, 1>(v);
  oem_pass<2, 2>(v);  oem_pass<2, 1>(v);
  oem_pass<4, 4>(v);  oem_pass<4, 2>(v);  oem_pass<4, 1>(v);
  oem_pass<8, 8>(v);  oem_pass<8, 4>(v);  oem_pass<8, 2>(v);  oem_pass<8, 1>(v);
  oem_pass<16, 16>(v); oem_pass<16, 8>(v); oem_pass<16, 4>(v);
  oem_pass<16, 2>(v);  oem_pass<16, 1>(v);
}

__global__ __launch_bounds__(256, 4)
void trimmed_gather(const _Float16* __restrict__ hblk, const int* __restrict__ nbrs,
                    float* __restrict__ out) {
  __shared__ int nb[16 * KNBR];
  const int bid   = blockIdx.x;
  const int g     = bid & 7;         // group fastest -> XCD g affinity
  const int chunk = bid >> 3;
  const int n0    = chunk * 16;
  const int t     = threadIdx.x;

  nb[t]       = nbrs[n0 * KNBR + t];
  nb[t + 256] = nbrs[n0 * KNBR + 256 + t];
  __syncthreads();

  const int nl = t >> 4;   // node local 0..15
  const int cp = t & 15;   // channel pair 0..15
  const size_t gbase = (size_t)g * NNODES * GRPC;

  h2 v[KNBR];
#pragma unroll
  for (int k = 0; k < KNBR; k++) {
    const int r = nb[nl * KNBR + k];
    v[k] = *(const h2*)&hblk[gbase + (size_t)r * GRPC + cp * 2];
  }

  sort32(v);

  float2 res;
  res.x = ((float)v[14][0] + (float)v[15][0] + (float)v[16][0] + (float)v[17][0]) * 0.25f;
  res.y = ((float)v[14][1] + (float)v[15][1] + (float)v[16][1] + (float)v[17][1]) * 0.25f;

  const int n = n0 + nl;
  *(float2*)&out[(size_t)n * D + g * GRPC + cp * 2] = res;
}

// ---------------------------------------------------------------------------
extern "C" void kernel_launch(void* const* d_in, const int* in_sizes, int n_in,
                              void* d_out, int out_size, void* d_ws, size_t ws_size,
                              hipStream_t stream) {
  const float* x    = (const float*)d_in[0];
  const int*   nbrs = (const int*)d_in[1];
  const float* W    = (const float*)d_in[2];
  float*       out  = (float*)d_out;

  _Float16* hblk = (_Float16*)d_ws;                                // 25.6 MB
  _Float16* Whi  = (_Float16*)((char*)d_ws + 25600000);            // 128 KB
  _Float16* Wlo  = Whi + 65536;                                    // 128 KB

  wcvt<<<dim3(64), dim3(256), 0, stream>>>(W, Whi, Wlo);
  gemm_mfma<<<dim3((NNODES + 63) / 64), dim3(256), 0, stream>>>(x, Whi, Wlo, hblk);
  trimmed_gather<<<dim3(NGRP * (NNODES / 16)), dim3(256), 0, stream>>>(
      hblk, nbrs, out);
}

// Round 6
// 223.303 us; speedup vs baseline: 5.0892x; 1.3088x over previous
//
#include <hip/hip_runtime.h>
#include <hip/hip_fp16.h>

#define D      256
#define NNODES 50000
#define KNBR   32
#define NGRP   8      // channel groups
#define GRPC   32     // channels per group

typedef _Float16 h8 __attribute__((ext_vector_type(8)));
typedef _Float16 h2 __attribute__((ext_vector_type(2)));
typedef float    f4 __attribute__((ext_vector_type(4)));

__device__ __forceinline__ h2 h2min(h2 a, h2 b) {
  h2 d; asm("v_pk_min_f16 %0, %1, %2" : "=v"(d) : "v"(a), "v"(b)); return d;
}
__device__ __forceinline__ h2 h2max(h2 a, h2 b) {
  h2 d; asm("v_pk_max_f16 %0, %1, %2" : "=v"(d) : "v"(a), "v"(b)); return d;
}

// global->LDS direct: LDS base MUST be wave-uniform (HW: base + lane*16).
__device__ __forceinline__ void gll16(const void* g, void* l) {
  __builtin_amdgcn_global_load_lds(
      (const __attribute__((address_space(1))) void*)g,
      (__attribute__((address_space(3))) void*)l, 16, 0, 0);
}

// ws layout:
//   h_blk : _Float16 [NGRP][NNODES][GRPC]          25,600,000 B
//   Whi   : _Float16 [256*256]                     at +25,600,000
//   Wlo   : _Float16 [256*256]                     at +25,731,072

// ---------------------------------------------------------------------------
// Kernel 0: split W into fp16 hi/lo pair (Whi + Wlo ~= W to ~2^-22 rel).
// ---------------------------------------------------------------------------
__global__ void wcvt(const float* __restrict__ W, _Float16* __restrict__ whi,
                     _Float16* __restrict__ wlo) {
  int i = (blockIdx.x * 256 + threadIdx.x) * 4;
  float4 w = *(const float4*)&W[i];
  float wf[4] = {w.x, w.y, w.z, w.w};
  union { _Float16 h[4]; uint2 u; } H, L;
#pragma unroll
  for (int e = 0; e < 4; e++) {
    _Float16 hi = (_Float16)wf[e];
    H.h[e] = hi;
    L.h[e] = (_Float16)(wf[e] - (float)hi);
  }
  *(uint2*)&whi[i] = H.u;
  *(uint2*)&wlo[i] = L.u;
}

// ---------------------------------------------------------------------------
// Kernel 1: h = x*W^T via 16x16x32 f16 MFMA, split-precision.
// Block = 64 rows x 256 cols, 4 waves. Per k-slice (32k): stage Whi/Wlo slice
// to LDS chunk-major [hsel][kq][col][8] via wave-uniform global_load_lds;
// B-frags from LDS (2-way bank aliasing = free); A (x row) prefetched in regs.
// ---------------------------------------------------------------------------
__global__ __launch_bounds__(256, 4)
void gemm_mfma(const float* __restrict__ x, const _Float16* __restrict__ Whi,
               const _Float16* __restrict__ Wlo, _Float16* __restrict__ hblk) {
  __shared__ _Float16 Ws[2][4][256][8];   // 32 KB: [hi/lo][kq][col][16B]

  const int tid  = threadIdx.x;
  const int lane = tid & 63;
  const int wv   = tid >> 6;
  const int wvu  = __builtin_amdgcn_readfirstlane(wv);  // provably uniform
  const int c    = lane & 15;   // fragment row (A) / col (B)
  const int ko   = lane >> 4;   // k-chunk 0..3
  const int brow = blockIdx.x * 64;

  int arow = brow + wv * 16 + c;
  if (arow >= NNODES) arow = NNODES - 1;   // clamp loads; stores guarded
  const float* xrow = &x[(size_t)arow * D];

  f4 acc[16];
#pragma unroll
  for (int j = 0; j < 16; j++) acc[j] = (f4)(0.f);

  // Stage k-slice t (32 k) of Whi+Wlo into Ws. Flat 16B unit
  // f = hsel*1024 + kq*256 + col; wave wvu covers f in [wvu*512, wvu*512+512).
  auto stage = [&](int t) {
    const int k0 = t * 32;
#pragma unroll
    for (int q = 0; q < 8; q++) {
      const int fb = wvu * 512 + q * 64;        // wave-uniform base unit
      const int f  = fb + lane;
      const int hsel = f >> 10;                  // uniform within wave
      const int kq   = (f >> 8) & 3;             // uniform within call
      const int col  = f & 255;                  // per-lane
      const _Float16* src = (hsel ? Wlo : Whi) + (size_t)col * D + k0 + kq * 8;
      gll16(src, (char*)Ws + (size_t)fb * 16);   // uniform LDS base
    }
  };

  stage(0);
  __syncthreads();

  float4 xa0 = *(const float4*)(xrow + ko * 8);
  float4 xa1 = *(const float4*)(xrow + ko * 8 + 4);

  for (int ks = 0; ks < 8; ks++) {
    float4 xb0, xb1;
    if (ks < 7) {   // prefetch next x chunk; latency hides under MFMAs
      xb0 = *(const float4*)(xrow + (ks + 1) * 32 + ko * 8);
      xb1 = *(const float4*)(xrow + (ks + 1) * 32 + ko * 8 + 4);
    }

    float xf[8] = {xa0.x, xa0.y, xa0.z, xa0.w, xa1.x, xa1.y, xa1.z, xa1.w};
    h8 ahi, alo;
#pragma unroll
    for (int e = 0; e < 8; e++) {
      _Float16 hi = (_Float16)xf[e];
      ahi[e] = hi;
      alo[e] = (_Float16)(xf[e] - (float)hi);
    }

#pragma unroll
    for (int j = 0; j < 16; j++) {
      h8 bhi = *(const h8*)&Ws[0][ko][j * 16 + c][0];
      h8 blo = *(const h8*)&Ws[1][ko][j * 16 + c][0];
      acc[j] = __builtin_amdgcn_mfma_f32_16x16x32_f16(ahi, bhi, acc[j], 0, 0, 0);
      acc[j] = __builtin_amdgcn_mfma_f32_16x16x32_f16(ahi, blo, acc[j], 0, 0, 0);
      acc[j] = __builtin_amdgcn_mfma_f32_16x16x32_f16(alo, bhi, acc[j], 0, 0, 0);
    }

    if (ks < 7) {
      __syncthreads();          // all waves done reading slice ks
      stage(ks + 1);
      __syncthreads();          // slice ks+1 landed (barrier drains vmcnt)
      xa0 = xb0; xa1 = xb1;
    }
  }

  // C/D layout (HW-verified): col = lane&15 (=c), row = (lane>>4)*4 + reg.
#pragma unroll
  for (int j = 0; j < 16; j++) {
    const int g  = j >> 1;
    const int oc = (j & 1) * 16 + c;
#pragma unroll
    for (int r = 0; r < 4; r++) {
      const int n = brow + wv * 16 + ko * 4 + r;
      if (n < NNODES)
        hblk[((size_t)g * NNODES + n) * GRPC + oc] = (_Float16)acc[j][r];
    }
  }
}

// ---------------------------------------------------------------------------
// Kernel 2: trimmed-mean gather, channel-group blocked (per-XCD L2 resident).
// Block = (group g, 16 nodes) x 256 threads; thread = (node, h2 pair).
// ---------------------------------------------------------------------------
template <int P, int K>
__device__ __forceinline__ void oem_pass(h2* v) {
#pragma unroll
  for (int j = K % P; j + K < 32; j += 2 * K) {
#pragma unroll
    for (int i = 0; i < K; i++) {
      if (i + j + K < 32 && ((i + j) / (2 * P) == (i + j + K) / (2 * P))) {
        h2 lo = h2min(v[i + j], v[i + j + K]);
        h2 hi = h2max(v[i + j], v[i + j + K]);
        v[i + j] = lo;
        v[i + j + K] = hi;
      }
    }
  }
}

__device__ __forceinline__ void sort32(h2* v) {
  oem_pass<1, 1>(v);
  oem_pass<2, 2>(v);  oem_pass<2, 1>(v);
  oem_pass<4, 4>(v);  oem_pass<4, 2>(v);  oem_pass<4, 1>(v);
  oem_pass<8, 8>(v);  oem_pass<8, 4>(v);  oem_pass<8, 2>(v);  oem_pass<8, 1>(v);
  oem_pass<16, 16>(v); oem_pass<16, 8>(v); oem_pass<16, 4>(v);
  oem_pass<16, 2>(v);  oem_pass<16, 1>(v);
}

__global__ __launch_bounds__(256, 4)
void trimmed_gather(const _Float16* __restrict__ hblk, const int* __restrict__ nbrs,
                    float* __restrict__ out) {
  __shared__ int nb[16 * KNBR];
  const int bid   = blockIdx.x;
  const int g     = bid & 7;         // group fastest -> XCD g affinity
  const int chunk = bid >> 3;
  const int n0    = chunk * 16;
  const int t     = threadIdx.x;

  nb[t]       = nbrs[n0 * KNBR + t];
  nb[t + 256] = nbrs[n0 * KNBR + 256 + t];
  __syncthreads();

  const int nl = t >> 4;   // node local 0..15
  const int cp = t & 15;   // channel pair 0..15
  const size_t gbase = (size_t)g * NNODES * GRPC;

  h2 v[KNBR];
#pragma unroll
  for (int k = 0; k < KNBR; k++) {
    const int r = nb[nl * KNBR + k];
    v[k] = *(const h2*)&hblk[gbase + (size_t)r * GRPC + cp * 2];
  }

  sort32(v);

  float2 res;
  res.x = ((float)v[14][0] + (float)v[15][0] + (float)v[16][0] + (float)v[17][0]) * 0.25f;
  res.y = ((float)v[14][1] + (float)v[15][1] + (float)v[16][1] + (float)v[17][1]) * 0.25f;

  const int n = n0 + nl;
  *(float2*)&out[(size_t)n * D + g * GRPC + cp * 2] = res;
}

// ---------------------------------------------------------------------------
extern "C" void kernel_launch(void* const* d_in, const int* in_sizes, int n_in,
                              void* d_out, int out_size, void* d_ws, size_t ws_size,
                              hipStream_t stream) {
  const float* x    = (const float*)d_in[0];
  const int*   nbrs = (const int*)d_in[1];
  const float* W    = (const float*)d_in[2];
  float*       out  = (float*)d_out;

  _Float16* hblk = (_Float16*)d_ws;                                // 25.6 MB
  _Float16* Whi  = (_Float16*)((char*)d_ws + 25600000);            // 128 KB
  _Float16* Wlo  = Whi + 65536;                                    // 128 KB

  wcvt<<<dim3(64), dim3(256), 0, stream>>>(W, Whi, Wlo);
  gemm_mfma<<<dim3((NNODES + 63) / 64), dim3(256), 0, stream>>>(x, Whi, Wlo, hblk);
  trimmed_gather<<<dim3(NGRP * (NNODES / 16)), dim3(256), 0, stream>>>(
      hblk, nbrs, out);
}

// Round 7
// 205.369 us; speedup vs baseline: 5.5336x; 1.0873x over previous
//
#include <hip/hip_runtime.h>
#include <hip/hip_fp16.h>

#define D      256
#define NNODES 50000
#define KNBR   32
#define NGRP   8      // channel groups
#define GRPC   32     // channels per group

typedef _Float16 h8 __attribute__((ext_vector_type(8)));
typedef _Float16 h4 __attribute__((ext_vector_type(4)));
typedef _Float16 h2 __attribute__((ext_vector_type(2)));
typedef float    f4 __attribute__((ext_vector_type(4)));

__device__ __forceinline__ h2 h2min(h2 a, h2 b) {
  h2 d; asm("v_pk_min_f16 %0, %1, %2" : "=v"(d) : "v"(a), "v"(b)); return d;
}
__device__ __forceinline__ h2 h2max(h2 a, h2 b) {
  h2 d; asm("v_pk_max_f16 %0, %1, %2" : "=v"(d) : "v"(a), "v"(b)); return d;
}

// global->LDS direct: LDS base MUST be wave-uniform (HW: base + lane*16).
__device__ __forceinline__ void gll16(const void* g, void* l) {
  __builtin_amdgcn_global_load_lds(
      (const __attribute__((address_space(1))) void*)g,
      (__attribute__((address_space(3))) void*)l, 16, 0, 0);
}

// ws layout:
//   h_blk : _Float16 [NGRP][NNODES][GRPC]   25,600,000 B
//   Whi   : _Float16 [256*256]              at +25,600,000 (131,072 B)

// ---------------------------------------------------------------------------
// Kernel 0: W (fp32) -> fp16.
// ---------------------------------------------------------------------------
__global__ void wcvt(const float* __restrict__ W, _Float16* __restrict__ whi) {
  int i = (blockIdx.x * 256 + threadIdx.x) * 4;
  float4 w = *(const float4*)&W[i];
  union { _Float16 h[4]; uint2 u; } H;
  H.h[0] = (_Float16)w.x; H.h[1] = (_Float16)w.y;
  H.h[2] = (_Float16)w.z; H.h[3] = (_Float16)w.w;
  *(uint2*)&whi[i] = H.u;
}

// ---------------------------------------------------------------------------
// Kernel 1: h = x*Whi^T via 16x16x32 f16 MFMA. x split as ahi+alo (exact),
// so h = x*fp16(W) to fp32 accuracy. Block = 128 rows x 128 cols, 4 waves;
// wave = 32 rows (2 tiles) x 8 col-tiles. Double-buffered LDS staging of the
// Whi k-slice via wave-uniform global_load_lds, overlapped with MFMAs; one
// __syncthreads per k-step (its vmcnt/lgkm drain is the fence we need).
// ---------------------------------------------------------------------------
__global__ __launch_bounds__(256, 4)
void gemm_mfma(const float* __restrict__ x, const _Float16* __restrict__ Whi,
               _Float16* __restrict__ hblk) {
  __shared__ _Float16 Ws[2][4][128][8];   // [buf][kq][colLocal][16B] = 2x8 KB

  const int tid  = threadIdx.x;
  const int lane = tid & 63;
  const int wv   = tid >> 6;
  const int wvu  = __builtin_amdgcn_readfirstlane(wv);
  const int c    = lane & 15;   // fragment row (A) / col (B)
  const int ko   = lane >> 4;   // k-chunk 0..3
  const int brow = blockIdx.x * 128;
  const int bcol = blockIdx.y * 128;

  const float* xrow[2];
#pragma unroll
  for (int tl = 0; tl < 2; tl++) {
    int ar = brow + wv * 32 + tl * 16 + c;
    if (ar >= NNODES) ar = NNODES - 1;
    xrow[tl] = &x[(size_t)ar * D];
  }

  f4 acc[2][8];
#pragma unroll
  for (int tl = 0; tl < 2; tl++)
#pragma unroll
    for (int j = 0; j < 8; j++) acc[tl][j] = (f4)(0.f);

  // Stage k-slice t of Whi (128 cols x 32 k = 8 KB = 512 x 16B units).
  // Unit u = kq*128 + colL; thread covers u = wvu*128 + q*64 + lane.
  auto stage = [&](int buf, int t) {
    const int k0 = t * 32;
#pragma unroll
    for (int q = 0; q < 2; q++) {
      const int fb   = wvu * 128 + q * 64;     // wave-uniform unit base
      const int f    = fb + lane;
      const int kq   = f >> 7;
      const int colL = f & 127;
      gll16(&Whi[(size_t)(bcol + colL) * D + k0 + kq * 8],
            (char*)Ws + ((size_t)buf * 512 + fb) * 16);
    }
  };

  stage(0, 0);
  __syncthreads();

  float4 xa[2][2], xb[2][2];
#pragma unroll
  for (int tl = 0; tl < 2; tl++) {
    xa[tl][0] = *(const float4*)(xrow[tl] + ko * 8);
    xa[tl][1] = *(const float4*)(xrow[tl] + ko * 8 + 4);
  }

  for (int t = 0; t < 8; ++t) {
    const int buf = t & 1;
    if (t < 7) {
      stage(buf ^ 1, t + 1);                   // issue next-slice loads
#pragma unroll
      for (int tl = 0; tl < 2; tl++) {
        xb[tl][0] = *(const float4*)(xrow[tl] + (t + 1) * 32 + ko * 8);
        xb[tl][1] = *(const float4*)(xrow[tl] + (t + 1) * 32 + ko * 8 + 4);
      }
    }

    h8 ahi[2], alo[2];
#pragma unroll
    for (int tl = 0; tl < 2; tl++) {
      float xf[8] = {xa[tl][0].x, xa[tl][0].y, xa[tl][0].z, xa[tl][0].w,
                     xa[tl][1].x, xa[tl][1].y, xa[tl][1].z, xa[tl][1].w};
#pragma unroll
      for (int e = 0; e < 8; e++) {
        _Float16 hi = (_Float16)xf[e];
        ahi[tl][e] = hi;
        alo[tl][e] = (_Float16)(xf[e] - (float)hi);
      }
    }

#pragma unroll
    for (int j = 0; j < 8; j++) {
      h8 bhi = *(const h8*)&Ws[buf][ko][j * 16 + c][0];
#pragma unroll
      for (int tl = 0; tl < 2; tl++) {
        acc[tl][j] = __builtin_amdgcn_mfma_f32_16x16x32_f16(ahi[tl], bhi, acc[tl][j], 0, 0, 0);
        acc[tl][j] = __builtin_amdgcn_mfma_f32_16x16x32_f16(alo[tl], bhi, acc[tl][j], 0, 0, 0);
      }
    }

    if (t < 7) {
      __syncthreads();   // drains vmcnt (staged loads landed) + rendezvous
#pragma unroll
      for (int tl = 0; tl < 2; tl++) { xa[tl][0] = xb[tl][0]; xa[tl][1] = xb[tl][1]; }
    }
  }

  // C/D layout (HW-verified): col = lane&15 (=c), row = ko*4 + r.
#pragma unroll
  for (int tl = 0; tl < 2; tl++)
#pragma unroll
    for (int j = 0; j < 8; j++) {
      const int g  = (bcol >> 5) + (j >> 1);
      const int oc = (j & 1) * 16 + c;
#pragma unroll
      for (int r = 0; r < 4; r++) {
        const int n = brow + wv * 32 + tl * 16 + ko * 4 + r;
        if (n < NNODES)
          hblk[((size_t)g * NNODES + n) * GRPC + oc] = (_Float16)acc[tl][j][r];
      }
    }
}

// ---------------------------------------------------------------------------
// Kernel 2: trimmed-mean gather, group-blocked (per-XCD L2 resident).
// Block = (group g, 32 nodes) x 256 threads; thread = (node, 4 channels).
// Selection network (170 CE): sort16 halves, bitonic cross, prune to
// {top-2 of low set} + {bottom-2 of high set} = ranks 14..17 as a set.
// ---------------------------------------------------------------------------
template <int N, int P, int K>
__device__ __forceinline__ void oem_pass(h2* v) {
#pragma unroll
  for (int j = K % P; j + K < N; j += 2 * K) {
#pragma unroll
    for (int i = 0; i < K; i++) {
      if (i + j + K < N && ((i + j) / (2 * P) == (i + j + K) / (2 * P))) {
        h2 lo = h2min(v[i + j], v[i + j + K]);
        h2 hi = h2max(v[i + j], v[i + j + K]);
        v[i + j] = lo;
        v[i + j + K] = hi;
      }
    }
  }
}

__device__ __forceinline__ void sort16(h2* v) {
  oem_pass<16, 1, 1>(v);
  oem_pass<16, 2, 2>(v);  oem_pass<16, 2, 1>(v);
  oem_pass<16, 4, 4>(v);  oem_pass<16, 4, 2>(v);  oem_pass<16, 4, 1>(v);
  oem_pass<16, 8, 8>(v);  oem_pass<16, 8, 4>(v);  oem_pass<16, 8, 2>(v);
  oem_pass<16, 8, 1>(v);
}

__device__ __forceinline__ void ce(h2* v, int a, int b) {
  h2 lo = h2min(v[a], v[b]);
  h2 hi = h2max(v[a], v[b]);
  v[a] = lo; v[b] = hi;
}

// After this, v[14]+v[15]+v[16]+v[17] = sum of ranks 14..17 of the 32 values.
__device__ __forceinline__ void select_mid4(h2* v) {
  sort16(v);
  sort16(v + 16);
#pragma unroll
  for (int i = 0; i < 16; i++) ce(v, i, 31 - i);   // L=v[0..15], H=v[16..31]
  // top-2 of L (bitonic)
#pragma unroll
  for (int i = 0; i < 8; i++) ce(v, i, i + 8);      // top-8 -> v[8..15]
#pragma unroll
  for (int i = 8; i < 12; i++) ce(v, i, i + 4);     // top-4 -> v[12..15]
  ce(v, 12, 14); ce(v, 13, 15);                     // top-2 -> v[14..15]
  // bottom-2 of H (bitonic)
#pragma unroll
  for (int i = 16; i < 24; i++) ce(v, i, i + 8);    // bot-8 -> v[16..23]
#pragma unroll
  for (int i = 16; i < 20; i++) ce(v, i, i + 4);    // bot-4 -> v[16..19]
  ce(v, 16, 18); ce(v, 17, 19);                     // bot-2 -> v[16..17]
}

__global__ __launch_bounds__(256, 4)
void trimmed_gather(const _Float16* __restrict__ hblk, const int* __restrict__ nbrs,
                    float* __restrict__ out) {
  __shared__ int nb[32 * KNBR];
  const int bid   = blockIdx.x;
  const int g     = bid & 7;         // group fastest -> XCD g affinity
  const int chunk = bid >> 3;
  const int n0    = chunk * 32;
  const int t     = threadIdx.x;

#pragma unroll
  for (int q = 0; q < 4; q++) {
    int idx = n0 * KNBR + q * 256 + t;
    if (idx >= NNODES * KNBR) idx = NNODES * KNBR - 1;   // tail clamp
    nb[q * 256 + t] = nbrs[idx];
  }
  __syncthreads();

  const int nl = t >> 3;   // node local 0..31
  const int cp = t & 7;    // channel quad 0..7
  const _Float16* base = hblk + (size_t)g * NNODES * GRPC + cp * 4;

  h2 va[KNBR], vb[KNBR];
#pragma unroll
  for (int k = 0; k < KNBR; k++) {
    const int r = nb[nl * KNBR + k];
    h4 w = *(const h4*)(base + (size_t)r * GRPC);
    va[k] = __builtin_shufflevector(w, w, 0, 1);
    vb[k] = __builtin_shufflevector(w, w, 2, 3);
  }

  select_mid4(va);
  select_mid4(vb);

  float4 res;
  res.x = ((float)va[14][0] + (float)va[15][0] + (float)va[16][0] + (float)va[17][0]) * 0.25f;
  res.y = ((float)va[14][1] + (float)va[15][1] + (float)va[16][1] + (float)va[17][1]) * 0.25f;
  res.z = ((float)vb[14][0] + (float)vb[15][0] + (float)vb[16][0] + (float)vb[17][0]) * 0.25f;
  res.w = ((float)vb[14][1] + (float)vb[15][1] + (float)vb[16][1] + (float)vb[17][1]) * 0.25f;

  const int n = n0 + nl;
  if (n < NNODES)
    *(float4*)&out[(size_t)n * D + g * GRPC + cp * 4] = res;
}

// ---------------------------------------------------------------------------
extern "C" void kernel_launch(void* const* d_in, const int* in_sizes, int n_in,
                              void* d_out, int out_size, void* d_ws, size_t ws_size,
                              hipStream_t stream) {
  const float* x    = (const float*)d_in[0];
  const int*   nbrs = (const int*)d_in[1];
  const float* W    = (const float*)d_in[2];
  float*       out  = (float*)d_out;

  _Float16* hblk = (_Float16*)d_ws;                       // 25.6 MB
  _Float16* Whi  = (_Float16*)((char*)d_ws + 25600000);   // 128 KB

  wcvt<<<dim3(64), dim3(256), 0, stream>>>(W, Whi);
  gemm_mfma<<<dim3((NNODES + 127) / 128, 2), dim3(256), 0, stream>>>(x, Whi, hblk);
  trimmed_gather<<<dim3(NGRP * ((NNODES + 31) / 32)), dim3(256), 0, stream>>>(
      hblk, nbrs, out);
}